// Round 6
// baseline (502.097 us; speedup 1.0000x reference)
//
#include <hip/hip_runtime.h>
#include <hip/hip_bf16.h>

// Matryoshka linear: y[m][n] = sum_k x[m][k] * W_seg[n_local][k]
//   seg0: n in [0,1024),    K=1024   seg1: n in [1024,2048), K=2048
//   seg2: n in [2048,4096), K=4096   M = 16384, out [16384][4096] f32
//
// Round 6: B bypasses LDS. W is pre-converted into MFMA-fragment-major
// layout (chunk(nb,kb) = 1KB contiguous = 64 lanes x 16B); the GEMM loads
// B-frags straight to registers (coalesced dwordx4, L2-resident), ping-pong
// prefetched 1 tile ahead. LDS holds only A (4-buffer rotation, prefetch 3,
// round-3 conflict-free XOR swizzle, ONE barrier + counted vmcnt(16)/tile).
// Per-tile LDS traffic drops 128 KB -> 80 KB; round-3 model predicts
// T_tile 2714 -> ~2250 cy.

typedef short bf16x8 __attribute__((ext_vector_type(8)));
typedef float f32x4 __attribute__((ext_vector_type(4)));

__device__ __forceinline__ ushort f2bf(float f) {
  union { float f; unsigned u; } c; c.f = f;
  unsigned u = c.u;
  unsigned r = u + 0x7fffu + ((u >> 16) & 1u);  // RNE
  return (ushort)(r >> 16);
}

__global__ void cvt_x_bf16(const float* __restrict__ in,
                           ushort* __restrict__ out, int n4) {
  int i = blockIdx.x * blockDim.x + threadIdx.x;
  int stride = gridDim.x * blockDim.x;
  const float4* in4 = (const float4*)in;
  ushort4* out4 = (ushort4*)out;
  for (int j = i; j < n4; j += stride) {
    float4 v = in4[j];
    ushort4 o;
    o.x = f2bf(v.x); o.y = f2bf(v.y); o.z = f2bf(v.z); o.w = f2bf(v.w);
    out4[j] = o;
  }
}

// W -> bf16 fragment-major: chunk(nb,kb) holds B-frag for n-block nb (16
// rows), k-block kb (32 cols): element [lane][j] = W[nb*16 + (lane&15)]
//                                                   [kb*32 + (lane>>4)*8 + j]
// Thread j handles 8 consecutive k of one row -> one contiguous 16B write.
__global__ void cvt_w_frag(const float* __restrict__ W0,
                           const float* __restrict__ W1,
                           const float* __restrict__ W2,
                           ushort* __restrict__ w0f,
                           ushort* __restrict__ w1f,
                           ushort* __restrict__ w2f) {
  const int T0 = 131072;             // 1024 rows * 128 k8
  const int T1 = T0 + 262144;        // 1024 * 256
  const int T2 = T1 + 1048576;       // 2048 * 512
  int i = blockIdx.x * blockDim.x + threadIdx.x;
  int stride = gridDim.x * blockDim.x;
  for (int j = i; j < T2; j += stride) {
    const float* W; ushort* Wf; int K, n, k8;
    if (j < T0)      { W = W0; Wf = w0f; K = 1024; n = j >> 7;         k8 = j & 127; }
    else if (j < T1) { W = W1; Wf = w1f; K = 2048; n = (j - T0) >> 8;  k8 = (j - T0) & 255; }
    else             { W = W2; Wf = w2f; K = 4096; n = (j - T1) >> 9;  k8 = (j - T1) & 511; }
    const int kb = k8 >> 2, hi = k8 & 3, nb = n >> 4, nl = n & 15;
    const size_t dst = ((size_t)(nb * (K >> 5) + kb) << 9) + (((hi << 4) | nl) << 3);
    const float4* s = (const float4*)(W + (size_t)n * K + (k8 << 3));
    float4 v0 = s[0], v1 = s[1];
    bf16x8 o;
    o[0] = (short)f2bf(v0.x); o[1] = (short)f2bf(v0.y);
    o[2] = (short)f2bf(v0.z); o[3] = (short)f2bf(v0.w);
    o[4] = (short)f2bf(v1.x); o[5] = (short)f2bf(v1.y);
    o[6] = (short)f2bf(v1.z); o[7] = (short)f2bf(v1.w);
    *(bf16x8*)(Wf + dst) = o;
  }
}

__device__ __forceinline__ void gload16(const ushort* g, const ushort* l) {
  __builtin_amdgcn_global_load_lds(
      (const __attribute__((address_space(1))) void*)g,
      (__attribute__((address_space(3))) void*)l, 16, 0, 0);
}

#define MF(av, bv, mi, ni) \
  acc[mi][ni] = __builtin_amdgcn_mfma_f32_16x16x32_bf16(av, bv, acc[mi][ni], 0, 0, 0)

__global__ __launch_bounds__(512, 2) void matry_gemm(
    const ushort* __restrict__ xbf,   // [16384][4096] bf16
    const ushort* __restrict__ w0f,   // frag-major
    const ushort* __restrict__ w1f,
    const ushort* __restrict__ w2f,
    float* __restrict__ out) {        // [16384][4096] f32
  __shared__ __align__(16) ushort sA[4][8192];   // 4 x 256x32 bf16 = 64 KB

  const int bid = blockIdx.x;
  const int rt = bid & 63;    // row tile fastest (A reuse on one XCD)
  const int ct = bid >> 6;

  int K; const ushort* Wf; int nl0;
  if (ct < 4)      { K = 1024; Wf = w0f; nl0 = ct * 256; }
  else if (ct < 8) { K = 2048; Wf = w1f; nl0 = (ct - 4) * 256; }
  else             { K = 4096; Wf = w2f; nl0 = (ct - 8) * 256; }
  const int NT = K >> 5;          // K-tiles of 32 (32/64/128 — always even)
  const int m0 = rt * 256;
  const int n0 = ct * 256;

  const int tid  = threadIdx.x;
  const int wid  = tid >> 6;
  const int lane = tid & 63;
  const int wm = wid >> 2;        // 0..1
  const int wn = wid & 3;         // 0..3
  const int fr = lane & 15;
  // round-3 conflict-free slot (verified 0 conflicts)
  const int swz_e = (((lane >> 4) ^ ((lane >> 1) & 3)) << 3);

  // A staging: pre-swizzled global source, linear LDS dest
  const int srow = tid >> 2;
  const int scol = (((tid & 3) ^ ((tid >> 3) & 3)) << 3);
  const ushort* Asrc0 = xbf + (size_t)(m0 + srow) * 4096 + scol;
  const ushort* Asrc1 = Asrc0 + (size_t)128 * 4096;
  const int d0 = tid * 8;
  const int d1 = 4096 + tid * 8;

  // B fragment base: chunk ((nl0>>4)+wn*4+ni)*NT + t, 512 ushorts, +lane*8
  const ushort* Bfw = Wf + (((size_t)((nl0 >> 4) + wn * 4) * NT) << 9) + lane * 8;

  f32x4 acc[8][4];
#pragma unroll
  for (int mi = 0; mi < 8; ++mi)
#pragma unroll
    for (int ni = 0; ni < 4; ++ni)
      acc[mi][ni] = (f32x4){0.f, 0.f, 0.f, 0.f};

  // ---- prologue: stage A tiles 0,1,2; load B(0) into bE ----
#pragma unroll
  for (int pt = 0; pt < 3; ++pt) {
    gload16(Asrc0 + pt * 32, &sA[pt][d0]);
    gload16(Asrc1 + pt * 32, &sA[pt][d1]);
  }
  bf16x8 bE[4], bO[4];
#pragma unroll
  for (int ni = 0; ni < 4; ++ni)
    bE[ni] = *(const bf16x8*)(Bfw + ((size_t)(ni * NT) << 9));
  asm volatile("s_waitcnt vmcnt(8)" ::: "memory");  // A tile 0 landed
  __builtin_amdgcn_s_barrier();

  // ---- main loop: 2 tiles/iter (ping-pong B regs), round-3 structure ----
  for (int t = 0; t < NT; t += 2) {
    // ===== tile t (even): consume bE, prefetch bO <- B(t+1) =====
    {
      const ushort* pa = &sA[t & 3][(wm * 128 + fr) * 32 + swz_e];
      bf16x8 a0 = *(const bf16x8*)(pa);
      bf16x8 a1 = *(const bf16x8*)(pa + 512);
      bf16x8 a2 = *(const bf16x8*)(pa + 1024);
      bf16x8 a3 = *(const bf16x8*)(pa + 1536);
      bf16x8 a4 = *(const bf16x8*)(pa + 2048);
      bf16x8 a5 = *(const bf16x8*)(pa + 2560);
      bf16x8 a6 = *(const bf16x8*)(pa + 3072);
      bf16x8 a7 = *(const bf16x8*)(pa + 3584);
      const int ts = (t + 3 < NT) ? (t + 3) : (NT - 1);  // clamped re-stage,
      const int bs = (t + 3) & 3;                        // lands in dead buf
      gload16(Asrc0 + (ts << 5), &sA[bs][d0]);
      gload16(Asrc1 + (ts << 5), &sA[bs][d1]);
#pragma unroll
      for (int ni = 0; ni < 4; ++ni)
        bO[ni] = *(const bf16x8*)(Bfw + ((size_t)(ni * NT + t + 1) << 9));
      __builtin_amdgcn_s_setprio(1);
      MF(a0, bE[0], 0, 0); MF(a0, bE[1], 0, 1); MF(a0, bE[2], 0, 2); MF(a0, bE[3], 0, 3);
      MF(a1, bE[0], 1, 0); MF(a1, bE[1], 1, 1); MF(a1, bE[2], 1, 2); MF(a1, bE[3], 1, 3);
      MF(a2, bE[0], 2, 0); MF(a2, bE[1], 2, 1); MF(a2, bE[2], 2, 2); MF(a2, bE[3], 2, 3);
      MF(a3, bE[0], 3, 0); MF(a3, bE[1], 3, 1); MF(a3, bE[2], 3, 2); MF(a3, bE[3], 3, 3);
      MF(a4, bE[0], 4, 0); MF(a4, bE[1], 4, 1); MF(a4, bE[2], 4, 2); MF(a4, bE[3], 4, 3);
      MF(a5, bE[0], 5, 0); MF(a5, bE[1], 5, 1); MF(a5, bE[2], 5, 2); MF(a5, bE[3], 5, 3);
      MF(a6, bE[0], 6, 0); MF(a6, bE[1], 6, 1); MF(a6, bE[2], 6, 2); MF(a6, bE[3], 6, 3);
      MF(a7, bE[0], 7, 0); MF(a7, bE[1], 7, 1); MF(a7, bE[2], 7, 2); MF(a7, bE[3], 7, 3);
      __builtin_amdgcn_s_setprio(0);
      // A-stage(t+1) (issued t-2) is oldest of: L(t-1)4 + S2+L4 + S2+L4 = 16
      asm volatile("s_waitcnt vmcnt(16)" ::: "memory");
      __builtin_amdgcn_s_barrier();
    }
    // ===== tile t+1 (odd): consume bO, prefetch bE <- B(t+2) =====
    {
      const ushort* pa = &sA[(t + 1) & 3][(wm * 128 + fr) * 32 + swz_e];
      bf16x8 a0 = *(const bf16x8*)(pa);
      bf16x8 a1 = *(const bf16x8*)(pa + 512);
      bf16x8 a2 = *(const bf16x8*)(pa + 1024);
      bf16x8 a3 = *(const bf16x8*)(pa + 1536);
      bf16x8 a4 = *(const bf16x8*)(pa + 2048);
      bf16x8 a5 = *(const bf16x8*)(pa + 2560);
      bf16x8 a6 = *(const bf16x8*)(pa + 3072);
      bf16x8 a7 = *(const bf16x8*)(pa + 3584);
      const int ts = (t + 4 < NT) ? (t + 4) : (NT - 1);
      const int bs = (t + 4) & 3;
      gload16(Asrc0 + (ts << 5), &sA[bs][d0]);
      gload16(Asrc1 + (ts << 5), &sA[bs][d1]);
      const int tl = (t + 2 < NT) ? (t + 2) : (NT - 1);  // clamp: last iter
#pragma unroll
      for (int ni = 0; ni < 4; ++ni)
        bE[ni] = *(const bf16x8*)(Bfw + ((size_t)(ni * NT + tl) << 9));
      __builtin_amdgcn_s_setprio(1);
      MF(a0, bO[0], 0, 0); MF(a0, bO[1], 0, 1); MF(a0, bO[2], 0, 2); MF(a0, bO[3], 0, 3);
      MF(a1, bO[0], 1, 0); MF(a1, bO[1], 1, 1); MF(a1, bO[2], 1, 2); MF(a1, bO[3], 1, 3);
      MF(a2, bO[0], 2, 0); MF(a2, bO[1], 2, 1); MF(a2, bO[2], 2, 2); MF(a2, bO[3], 2, 3);
      MF(a3, bO[0], 3, 0); MF(a3, bO[1], 3, 1); MF(a3, bO[2], 3, 2); MF(a3, bO[3], 3, 3);
      MF(a4, bO[0], 4, 0); MF(a4, bO[1], 4, 1); MF(a4, bO[2], 4, 2); MF(a4, bO[3], 4, 3);
      MF(a5, bO[0], 5, 0); MF(a5, bO[1], 5, 1); MF(a5, bO[2], 5, 2); MF(a5, bO[3], 5, 3);
      MF(a6, bO[0], 6, 0); MF(a6, bO[1], 6, 1); MF(a6, bO[2], 6, 2); MF(a6, bO[3], 6, 3);
      MF(a7, bO[0], 7, 0); MF(a7, bO[1], 7, 1); MF(a7, bO[2], 7, 2); MF(a7, bO[3], 7, 3);
      __builtin_amdgcn_s_setprio(0);
      asm volatile("s_waitcnt vmcnt(16)" ::: "memory");
      __builtin_amdgcn_s_barrier();
    }
  }

  // ---- epilogue: C/D layout col=lane&15, row=(lane>>4)*4+reg [m89] ----
  const int rq = (lane >> 4) * 4;
#pragma unroll
  for (int mi = 0; mi < 8; ++mi) {
#pragma unroll
    for (int ni = 0; ni < 4; ++ni) {
      const int n = n0 + wn * 64 + ni * 16 + fr;
#pragma unroll
      for (int r = 0; r < 4; ++r) {
        const int m = m0 + wm * 128 + mi * 16 + rq + r;
        out[(size_t)m * 4096 + n] = acc[mi][ni][r];
      }
    }
  }
}

// Correct-but-slow fallback if workspace is too small.
__global__ void naive_kernel(const float* __restrict__ x,
                             const float* __restrict__ W0,
                             const float* __restrict__ W1,
                             const float* __restrict__ W2,
                             float* __restrict__ out) {
  long idx = (long)blockIdx.x * 256 + threadIdx.x;
  int n = (int)(idx & 4095);
  long m = idx >> 12;
  int K; const float* W; int nl;
  if (n < 1024)      { K = 1024; W = W0; nl = n; }
  else if (n < 2048) { K = 2048; W = W1; nl = n - 1024; }
  else               { K = 4096; W = W2; nl = n - 2048; }
  const float* xr = x + m * 4096;
  const float* wr = W + (long)nl * K;
  float s = 0.f;
  for (int k = 0; k < K; ++k) s += xr[k] * wr[k];
  out[idx] = s;
}

extern "C" void kernel_launch(void* const* d_in, const int* in_sizes, int n_in,
                              void* d_out, int out_size, void* d_ws,
                              size_t ws_size, hipStream_t stream) {
  const float* x  = (const float*)d_in[0];
  const float* W0 = (const float*)d_in[1];
  const float* W1 = (const float*)d_in[2];
  const float* W2 = (const float*)d_in[3];
  float* out = (float*)d_out;

  const size_t xN  = (size_t)16384 * 4096;
  const size_t w0N = (size_t)1024 * 1024;
  const size_t w1N = (size_t)1024 * 2048;
  const size_t w2N = (size_t)2048 * 4096;
  const size_t need = (xN + w0N + w1N + w2N) * sizeof(ushort);  // ~150 MB

  if (ws_size >= need) {
    ushort* xbf = (ushort*)d_ws;
    ushort* w0f = xbf + xN;
    ushort* w1f = w0f + w0N;
    ushort* w2f = w1f + w1N;
    cvt_x_bf16<<<2048, 256, 0, stream>>>(x, xbf, (int)(xN >> 2));
    cvt_w_frag<<<2048, 256, 0, stream>>>(W0, W1, W2, w0f, w1f, w2f);
    matry_gemm<<<1024, 512, 0, stream>>>(xbf, w0f, w1f, w2f, out);
  } else {
    naive_kernel<<<(int)((xN + 255) / 256), 256, 0, stream>>>(x, W0, W1, W2, out);
  }
}